// Round 5
// baseline (324.705 us; speedup 1.0000x reference)
//
#include <hip/hip_runtime.h>
#include <math.h>

using f16   = _Float16;
using f16x4 = __attribute__((ext_vector_type(4))) _Float16;
using f16x8 = __attribute__((ext_vector_type(8))) _Float16;
using f32x4 = __attribute__((ext_vector_type(4))) float;

#define NW    343           // tokens per window (7*7*7)
#define NWP   352           // padded to 22*16
#define KSP   40            // Ks LDS pitch (f16): 80B row stride -> 8 bank-groups
#define VTP   356           // V^T LDS pitch
#define HEADS 8
#define MTOT  43904         // 128 windows * 343
#define LOG2E 1.4426950408889634f
#define QSC   (0.17677669529663687f * 1.4426950408889634f)  // dh^-0.5 * log2(e)

typedef const __attribute__((address_space(1))) unsigned int* gp1_t;
typedef __attribute__((address_space(3))) unsigned int* lp3_t;
__device__ __forceinline__ void gload_lds16(const void* g, void* l) {
    __builtin_amdgcn_global_load_lds((gp1_t)g, (lp3_t)l, 16, 0, 0);
}

// ---------------- converts ----------------
__global__ void cvt_x(const float* __restrict__ x, f16* __restrict__ xb) {
    int id = blockIdx.x * 256 + threadIdx.x;
    float4 v = *(const float4*)(x + id * 4);
    f16x4 o = { (f16)v.x, (f16)v.y, (f16)v.z, (f16)v.w };
    *(f16x4*)(xb + id * 4) = o;
}

// merged: wqkv^T (scaled q cols) | wout^T | padded bias table
__global__ void prep_k(const float* __restrict__ wqkv, const float* __restrict__ wout,
                       const float* __restrict__ tab,
                       f16* __restrict__ wqkvT, f16* __restrict__ woutT,
                       float* __restrict__ bp) {
    int b = blockIdx.x, t = threadIdx.x;
    if (b < 768) {                     // wqkv: n = b, k = t
        float v = wqkv[t * 768 + b];
        if (b < 256) v *= QSC;
        wqkvT[b * 256 + t] = (f16)v;
    } else if (b < 1024) {             // wout: n = b-768
        int n = b - 768;
        woutT[n * 256 + t] = (f16)wout[t * 256 + n];
    } else {                           // bias: bp[h][i][j]
        int id = (b - 1024) * 256 + t; // 8*352*352 exact
        int h = id / (NWP * NWP);
        int rem = id - h * NWP * NWP;
        int i = rem / NWP, j = rem - (rem / NWP) * NWP;
        float v;
        if (j >= NW) v = -1e30f;       // masked key col -> exp2 = 0
        else if (i >= NW) v = 0.f;
        else {
            int a1 = i / 49, a2 = (i / 7) % 7, a3 = i % 7;
            int b1 = j / 49, b2 = (j / 7) % 7, b3 = j % 7;
            int idx = (a1 - b1 + 6) * 169 + (a2 - b2 + 6) * 13 + (a3 - b3 + 6);
            v = tab[idx * 8 + h] * LOG2E;
        }
        bp[id] = v;
    }
}

// ---- GEMM: C(M x N) = A(M x 256) * Bt(N x 256)^T, 128x128 tile, BK=64, lds-DMA ----
// LDS layout is column-block rotated: slot (row, sb) holds global 8-f16 block
// (sb - row) & 7. DMA dest stays linear (lane*16) -- the swizzle is applied to
// the *source* address; ds_read_b128 then hits 8 distinct bank-groups across rows.
template<bool OUT_F32>
__launch_bounds__(256, 3)
__global__ void gemm_k(const f16* __restrict__ A, const f16* __restrict__ Bt,
                       void* __restrict__ Cp, int N) {
    __shared__ f16 As[128 * 64];
    __shared__ f16 Bs[128 * 64];
    const int m0 = blockIdx.x * 128;
    const int n0 = blockIdx.y * 128;
    const int t = threadIdx.x;
    const int wave = t >> 6, lane = t & 63;
    const int q = lane >> 4, c = lane & 15;
    const int wm = (wave >> 1) * 64, wn = (wave & 1) * 64;
    const int sr = t >> 3;          // 0..31: row within a 32-row staging group
    const int sb = t & 7;           // LDS col-block slot 0..7

    f32x4 acc[4][4] = {};
#pragma unroll
    for (int ks = 0; ks < 256; ks += 64) {
#pragma unroll
        for (int j = 0; j < 4; j++) {
            int row = j * 32 + sr;
            int gb = (sb - row) & 7;                       // rotated source block
            gload_lds16(&A[(size_t)(m0 + row) * 256 + ks + gb * 8], &As[row * 64 + sb * 8]);
            gload_lds16(&Bt[(size_t)(n0 + row) * 256 + ks + gb * 8], &Bs[row * 64 + sb * 8]);
        }
        __syncthreads();
#pragma unroll
        for (int ko = 0; ko < 2; ko++) {
            f16x8 af[4], bf[4];
#pragma unroll
            for (int a = 0; a < 4; a++) {
                int row = wm + a * 16 + c;
                af[a] = *(const f16x8*)&As[row * 64 + ((ko * 4 + q + row) & 7) * 8];
            }
#pragma unroll
            for (int b = 0; b < 4; b++) {
                int row = wn + b * 16 + c;
                bf[b] = *(const f16x8*)&Bs[row * 64 + ((ko * 4 + q + row) & 7) * 8];
            }
#pragma unroll
            for (int a = 0; a < 4; a++)
#pragma unroll
                for (int b = 0; b < 4; b++)
                    acc[a][b] = __builtin_amdgcn_mfma_f32_16x16x32_f16(af[a], bf[b], acc[a][b], 0, 0, 0);
        }
        __syncthreads();
    }
#pragma unroll
    for (int a = 0; a < 4; a++)
#pragma unroll
        for (int b = 0; b < 4; b++) {
            int row0 = m0 + wm + a * 16 + q * 4;
            int col = n0 + wn + b * 16 + c;
#pragma unroll
            for (int r = 0; r < 4; r++) {
                float v = acc[a][b][r];
                if (OUT_F32) ((float*)Cp)[(size_t)(row0 + r) * N + col] = v;
                else         ((f16*)Cp)[(size_t)(row0 + r) * N + col] = (f16)v;
            }
        }
}

// -------- fused attention: 1 block = (window, head), 8 waves share K/V LDS --------
// Max-free softmax (logits O(10); masked keys bias=-1e30 -> p=0). Bias rides the
// MFMA C operand. j-loop split into even/odd chains (independent accumulators)
// to double ILP on the PV accumulator recurrence.
__launch_bounds__(512, 4)
__global__ void attn_k(const f16* __restrict__ qkv, const float* __restrict__ biasP,
                       f16* __restrict__ ctx) {
    const int w = blockIdx.x >> 3;
    const int h = blockIdx.x & 7;
    __shared__ f16 Ks[NWP * KSP];      // [key][feat], padded pitch 40
    __shared__ f16 Vt[32 * VTP];       // [dh][key] (transposed)
    const int t = threadIdx.x;
    const size_t base = (size_t)(w * NW) * 768;

    for (int u = t; u < NWP * 4; u += 512) {
        int row = u >> 2, un = u & 3;
        uint4 val;
        if (row < NW) val = *(const uint4*)&qkv[base + (size_t)row * 768 + 256 + h * 32 + un * 8];
        else { val.x = val.y = val.z = val.w = 0u; }
        *(uint4*)&Ks[row * KSP + un * 8] = val;
    }
    for (int u = t; u < NWP * 4; u += 512) {
        int row = u >> 2, un = u & 3;
        if (row < NW) {
            uint4 val = *(const uint4*)&qkv[base + (size_t)row * 768 + 512 + h * 32 + un * 8];
            const f16* pv = (const f16*)&val;
#pragma unroll
            for (int e = 0; e < 8; e++) Vt[(un * 8 + e) * VTP + row] = pv[e];
        } else {
#pragma unroll
            for (int e = 0; e < 8; e++) Vt[(un * 8 + e) * VTP + row] = (f16)0.f;
        }
    }
    __syncthreads();

    const int wave = t >> 6, lane = t & 63;
    const int q = lane >> 4, c = lane & 15;
    const float* biasH = biasP + (size_t)h * NWP * NWP;

    for (int qt = wave; qt < NWP / 16; qt += 8) {
        const int iq = qt * 16 + c;                 // this lane's query (col axis)
        const int iqc = iq < NW ? iq : NW - 1;
        f16x8 qf = *(const f16x8*)&qkv[base + (size_t)iqc * 768 + h * 32 + q * 8];
        const float* brow = biasH + (size_t)iq * NWP;

        f32x4 o0a = {0.f,0.f,0.f,0.f}, o1a = {0.f,0.f,0.f,0.f};
        f32x4 o0b = {0.f,0.f,0.f,0.f}, o1b = {0.f,0.f,0.f,0.f};
        float lsa = 0.f, lsb = 0.f;
#pragma unroll
        for (int jp = 0; jp < NWP / 32; jp++) {
            {   // chain A: jt = 2*jp
                const int jb = (2 * jp) * 16;
                f16x8 kf = *(const f16x8*)&Ks[(jb + c) * KSP + q * 8];
                f32x4 b4 = *(const f32x4*)&brow[jb + q * 4];
                f32x4 s = __builtin_amdgcn_mfma_f32_16x16x32_f16(kf, qf, b4, 0, 0, 0);
                float p0 = __builtin_amdgcn_exp2f(s[0]);
                float p1 = __builtin_amdgcn_exp2f(s[1]);
                float p2 = __builtin_amdgcn_exp2f(s[2]);
                float p3 = __builtin_amdgcn_exp2f(s[3]);
                lsa += (p0 + p1) + (p2 + p3);
                f16x4 pf = { (f16)p0, (f16)p1, (f16)p2, (f16)p3 };
                f16x4 v0 = *(const f16x4*)&Vt[c * VTP + jb + q * 4];
                f16x4 v1 = *(const f16x4*)&Vt[(16 + c) * VTP + jb + q * 4];
                o0a = __builtin_amdgcn_mfma_f32_16x16x16f16(v0, pf, o0a, 0, 0, 0);
                o1a = __builtin_amdgcn_mfma_f32_16x16x16f16(v1, pf, o1a, 0, 0, 0);
            }
            {   // chain B: jt = 2*jp+1 (independent accumulators)
                const int jb = (2 * jp + 1) * 16;
                f16x8 kf = *(const f16x8*)&Ks[(jb + c) * KSP + q * 8];
                f32x4 b4 = *(const f32x4*)&brow[jb + q * 4];
                f32x4 s = __builtin_amdgcn_mfma_f32_16x16x32_f16(kf, qf, b4, 0, 0, 0);
                float p0 = __builtin_amdgcn_exp2f(s[0]);
                float p1 = __builtin_amdgcn_exp2f(s[1]);
                float p2 = __builtin_amdgcn_exp2f(s[2]);
                float p3 = __builtin_amdgcn_exp2f(s[3]);
                lsb += (p0 + p1) + (p2 + p3);
                f16x4 pf = { (f16)p0, (f16)p1, (f16)p2, (f16)p3 };
                f16x4 v0 = *(const f16x4*)&Vt[c * VTP + jb + q * 4];
                f16x4 v1 = *(const f16x4*)&Vt[(16 + c) * VTP + jb + q * 4];
                o0b = __builtin_amdgcn_mfma_f32_16x16x16f16(v0, pf, o0b, 0, 0, 0);
                o1b = __builtin_amdgcn_mfma_f32_16x16x16f16(v1, pf, o1b, 0, 0, 0);
            }
        }
        float lsum = lsa + lsb;
        lsum += __shfl_xor(lsum, 16);   // reduce over quads, once per q-tile
        lsum += __shfl_xor(lsum, 32);

        if (iq < NW) {
            float inv = 1.f / lsum;
            size_t ob = (size_t)(w * NW + iq) * 256 + h * 32;
            f16x4 s0 = { (f16)((o0a[0] + o0b[0]) * inv), (f16)((o0a[1] + o0b[1]) * inv),
                         (f16)((o0a[2] + o0b[2]) * inv), (f16)((o0a[3] + o0b[3]) * inv) };
            f16x4 s1 = { (f16)((o1a[0] + o1b[0]) * inv), (f16)((o1a[1] + o1b[1]) * inv),
                         (f16)((o1a[2] + o1b[2]) * inv), (f16)((o1a[3] + o1b[3]) * inv) };
            *(f16x4*)&ctx[ob + q * 4] = s0;
            *(f16x4*)&ctx[ob + 16 + q * 4] = s1;
        }
    }
}

// ---------------- launch ----------------
extern "C" void kernel_launch(void* const* d_in, const int* in_sizes, int n_in,
                              void* d_out, int out_size, void* d_ws, size_t ws_size,
                              hipStream_t stream) {
    const float* x    = (const float*)d_in[0];
    const float* wqkv = (const float*)d_in[1];
    const float* wout = (const float*)d_in[2];
    const float* tab  = (const float*)d_in[3];

    char* ws = (char*)d_ws;
    size_t off = 0;
    f16*   xb     = (f16*)(ws + off);   off += (size_t)MTOT * 256 * 2;
    f16*   wqkvT  = (f16*)(ws + off);   off += (size_t)768 * 256 * 2;
    f16*   woutT  = (f16*)(ws + off);   off += (size_t)256 * 256 * 2;
    float* biasP  = (float*)(ws + off); off += (size_t)8 * NWP * NWP * 4;
    f16*   qkvb   = (f16*)(ws + off);   off += (size_t)MTOT * 768 * 2;
    f16*   ctxb   = (f16*)(ws + off);   off += (size_t)MTOT * 256 * 2;
    if (ws_size < off) return;

    cvt_x <<<MTOT * 256 / 1024, 256, 0, stream>>>(x, xb);
    prep_k<<<1024 + 8 * NWP * NWP / 256, 256, 0, stream>>>(wqkv, wout, tab, wqkvT, woutT, biasP);
    gemm_k<false><<<dim3(MTOT / 128, 768 / 128), 256, 0, stream>>>(xb, wqkvT, qkvb, 768);
    attn_k<<<128 * HEADS, 512, 0, stream>>>(qkvb, biasP, ctxb);
    gemm_k<true><<<dim3(MTOT / 128, 256 / 128), 256, 0, stream>>>(ctxb, woutT, d_out, 256);
}

// Round 6
// 250.503 us; speedup vs baseline: 1.2962x; 1.2962x over previous
//
#include <hip/hip_runtime.h>
#include <math.h>

using f16   = _Float16;
using f16x4 = __attribute__((ext_vector_type(4))) _Float16;
using f16x8 = __attribute__((ext_vector_type(8))) _Float16;
using f32x4 = __attribute__((ext_vector_type(4))) float;

#define NW    343           // tokens per window (7*7*7)
#define NWP   352           // padded to 22*16
#define VTP   356           // V^T LDS pitch (even -> b32 pair-writes stay aligned)
#define HEADS 8
#define MTOT  43904         // 128 windows * 343
#define LOG2E 1.4426950408889634f
#define QSC   (0.17677669529663687f * 1.4426950408889634f)  // dh^-0.5 * log2(e)

typedef const __attribute__((address_space(1))) unsigned int* gp1_t;
typedef __attribute__((address_space(3))) unsigned int* lp3_t;
__device__ __forceinline__ void gload_lds16(const void* g, void* l) {
    __builtin_amdgcn_global_load_lds((gp1_t)g, (lp3_t)l, 16, 0, 0);
}

// ---------------- converts ----------------
__global__ void cvt_x(const float* __restrict__ x, f16* __restrict__ xb) {
    int id = blockIdx.x * 256 + threadIdx.x;
    float4 v = *(const float4*)(x + id * 4);
    f16x4 o = { (f16)v.x, (f16)v.y, (f16)v.z, (f16)v.w };
    *(f16x4*)(xb + id * 4) = o;
}

// merged: wqkv^T (scaled q cols) | wout^T | padded bias table
__global__ void prep_k(const float* __restrict__ wqkv, const float* __restrict__ wout,
                       const float* __restrict__ tab,
                       f16* __restrict__ wqkvT, f16* __restrict__ woutT,
                       float* __restrict__ bp) {
    int b = blockIdx.x, t = threadIdx.x;
    if (b < 768) {                     // wqkv: n = b, k = t
        float v = wqkv[t * 768 + b];
        if (b < 256) v *= QSC;
        wqkvT[b * 256 + t] = (f16)v;
    } else if (b < 1024) {             // wout: n = b-768
        int n = b - 768;
        woutT[n * 256 + t] = (f16)wout[t * 256 + n];
    } else {                           // bias: bp[h][i][j]
        int id = (b - 1024) * 256 + t; // 8*352*352 exact
        int h = id / (NWP * NWP);
        int rem = id - h * NWP * NWP;
        int i = rem / NWP, j = rem - (rem / NWP) * NWP;
        float v;
        if (j >= NW) v = -1e30f;       // masked key col -> exp2 = 0
        else if (i >= NW) v = 0.f;
        else {
            int a1 = i / 49, a2 = (i / 7) % 7, a3 = i % 7;
            int b1 = j / 49, b2 = (j / 7) % 7, b3 = j % 7;
            int idx = (a1 - b1 + 6) * 169 + (a2 - b2 + 6) * 13 + (a3 - b3 + 6);
            v = tab[idx * 8 + h] * LOG2E;
        }
        bp[id] = v;
    }
}

// ---- GEMM: C(M x N) = A(M x 256) * Bt(N x 256)^T, 128x128 tile, BK=32, lds-DMA ----
// (R4 version: BK=64 + swizzle measured neutral in R5; keep the known-good one.)
template<bool OUT_F32>
__launch_bounds__(256)
__global__ void gemm_k(const f16* __restrict__ A, const f16* __restrict__ Bt,
                       void* __restrict__ Cp, int N) {
    __shared__ f16 As[128 * 32];
    __shared__ f16 Bs[128 * 32];
    const int m0 = blockIdx.x * 128;
    const int n0 = blockIdx.y * 128;
    const int t = threadIdx.x;
    const int wave = t >> 6, lane = t & 63;
    const int q = lane >> 4, c = lane & 15;
    const int wm = (wave >> 1) * 64, wn = (wave & 1) * 64;
    const int r0 = t >> 2;
    const int c8 = (t & 3) * 8;

    f32x4 acc[4][4] = {};
#pragma unroll
    for (int ks = 0; ks < 256; ks += 32) {
        gload_lds16(&A[(size_t)(m0 + r0) * 256 + ks + c8],        &As[r0 * 32 + c8]);
        gload_lds16(&A[(size_t)(m0 + r0 + 64) * 256 + ks + c8],   &As[(r0 + 64) * 32 + c8]);
        gload_lds16(&Bt[(size_t)(n0 + r0) * 256 + ks + c8],       &Bs[r0 * 32 + c8]);
        gload_lds16(&Bt[(size_t)(n0 + r0 + 64) * 256 + ks + c8],  &Bs[(r0 + 64) * 32 + c8]);
        __syncthreads();
        f16x8 af[4], bf[4];
#pragma unroll
        for (int a = 0; a < 4; a++) af[a] = *(const f16x8*)&As[(wm + a * 16 + c) * 32 + q * 8];
#pragma unroll
        for (int b = 0; b < 4; b++) bf[b] = *(const f16x8*)&Bs[(wn + b * 16 + c) * 32 + q * 8];
#pragma unroll
        for (int a = 0; a < 4; a++)
#pragma unroll
            for (int b = 0; b < 4; b++)
                acc[a][b] = __builtin_amdgcn_mfma_f32_16x16x32_f16(af[a], bf[b], acc[a][b], 0, 0, 0);
        __syncthreads();
    }
#pragma unroll
    for (int a = 0; a < 4; a++)
#pragma unroll
        for (int b = 0; b < 4; b++) {
            int row0 = m0 + wm + a * 16 + q * 4;
            int col = n0 + wn + b * 16 + c;
#pragma unroll
            for (int r = 0; r < 4; r++) {
                float v = acc[a][b][r];
                if (OUT_F32) ((float*)Cp)[(size_t)(row0 + r) * N + col] = v;
                else         ((f16*)Cp)[(size_t)(row0 + r) * N + col] = (f16)v;
            }
        }
}

// -------- fused attention: 1 block = (window, head), 8 waves share K/V LDS --------
// Max-free softmax (logits O(10); masked keys bias=-1e30 -> p=0). Bias rides the
// MFMA C operand. NOTE: no min-waves arg on launch_bounds -- (512,4) in R5 forced
// VGPR=64 and spilled (337MB fetch); plain 512 lands at VGPR=128, no spill.
__launch_bounds__(512)
__global__ void attn_k(const f16* __restrict__ qkv, const float* __restrict__ biasP,
                       f16* __restrict__ ctx) {
    const int w = blockIdx.x >> 3;
    const int h = blockIdx.x & 7;
    __shared__ f16 Ks[NWP * 32];       // [key][feat]
    __shared__ f16 Vt[32 * VTP];       // [dh][key] (transposed)
    const int t = threadIdx.x;
    const size_t base = (size_t)(w * NW) * 768;

    for (int u = t; u < NWP * 4; u += 512) {
        int row = u >> 2, un = u & 3;
        uint4 val;
        if (row < NW) val = *(const uint4*)&qkv[base + (size_t)row * 768 + 256 + h * 32 + un * 8];
        else { val.x = val.y = val.z = val.w = 0u; }
        *(uint4*)&Ks[row * 32 + un * 8] = val;
    }
    // V^T staging: token-pair packed b32 writes (half the LDS write count of b16 scatter)
    for (int u = t; u < (NWP / 2) * 4; u += 512) {
        int pr = u >> 2, un = u & 3;
        int row = pr * 2;
        uint4 v0, v1;
        v0.x = v0.y = v0.z = v0.w = 0u;
        v1 = v0;
        if (row < NW)     v0 = *(const uint4*)&qkv[base + (size_t)row * 768 + 512 + h * 32 + un * 8];
        if (row + 1 < NW) v1 = *(const uint4*)&qkv[base + (size_t)(row + 1) * 768 + 512 + h * 32 + un * 8];
        const unsigned short* a = (const unsigned short*)&v0;
        const unsigned short* b = (const unsigned short*)&v1;
#pragma unroll
        for (int e = 0; e < 8; e++) {
            unsigned int packed = (unsigned int)a[e] | ((unsigned int)b[e] << 16);
            *(unsigned int*)&Vt[(un * 8 + e) * VTP + row] = packed;
        }
    }
    __syncthreads();

    const int wave = t >> 6, lane = t & 63;
    const int q = lane >> 4, c = lane & 15;
    const float* biasH = biasP + (size_t)h * NWP * NWP;

    for (int qt = wave; qt < NWP / 16; qt += 8) {
        const int iq = qt * 16 + c;                 // this lane's query (col axis)
        const int iqc = iq < NW ? iq : NW - 1;
        f16x8 qf = *(const f16x8*)&qkv[base + (size_t)iqc * 768 + h * 32 + q * 8];
        const float* brow = biasH + (size_t)iq * NWP;

        f32x4 o0 = {0.f, 0.f, 0.f, 0.f}, o1 = {0.f, 0.f, 0.f, 0.f};
        float lsum = 0.f;
#pragma unroll
        for (int jt = 0; jt < NWP / 16; jt++) {
            const int jb = jt * 16;
            // S^T tile: rows = keys (reg axis), cols = queries (lane axis); C = bias
            f16x8 kf = *(const f16x8*)&Ks[(jb + c) * 32 + q * 8];
            f32x4 b4 = *(const f32x4*)&brow[jb + q * 4];
            f32x4 s = __builtin_amdgcn_mfma_f32_16x16x32_f16(kf, qf, b4, 0, 0, 0);
            float p0 = __builtin_amdgcn_exp2f(s[0]);
            float p1 = __builtin_amdgcn_exp2f(s[1]);
            float p2 = __builtin_amdgcn_exp2f(s[2]);
            float p3 = __builtin_amdgcn_exp2f(s[3]);
            lsum += (p0 + p1) + (p2 + p3);
            // P regs are already the B-operand of P^T for 16x16x16: O^T += V^T P^T
            f16x4 pf = { (f16)p0, (f16)p1, (f16)p2, (f16)p3 };
            f16x4 v0 = *(const f16x4*)&Vt[c * VTP + jb + q * 4];
            f16x4 v1 = *(const f16x4*)&Vt[(16 + c) * VTP + jb + q * 4];
            o0 = __builtin_amdgcn_mfma_f32_16x16x16f16(v0, pf, o0, 0, 0, 0);
            o1 = __builtin_amdgcn_mfma_f32_16x16x16f16(v1, pf, o1, 0, 0, 0);
        }
        lsum += __shfl_xor(lsum, 16);   // reduce over quads, once per q-tile
        lsum += __shfl_xor(lsum, 32);

        if (iq < NW) {
            float inv = 1.f / lsum;
            size_t ob = (size_t)(w * NW + iq) * 256 + h * 32;
            f16x4 s0 = { (f16)(o0[0] * inv), (f16)(o0[1] * inv),
                         (f16)(o0[2] * inv), (f16)(o0[3] * inv) };
            f16x4 s1 = { (f16)(o1[0] * inv), (f16)(o1[1] * inv),
                         (f16)(o1[2] * inv), (f16)(o1[3] * inv) };
            *(f16x4*)&ctx[ob + q * 4] = s0;
            *(f16x4*)&ctx[ob + 16 + q * 4] = s1;
        }
    }
}

// ---------------- launch ----------------
extern "C" void kernel_launch(void* const* d_in, const int* in_sizes, int n_in,
                              void* d_out, int out_size, void* d_ws, size_t ws_size,
                              hipStream_t stream) {
    const float* x    = (const float*)d_in[0];
    const float* wqkv = (const float*)d_in[1];
    const float* wout = (const float*)d_in[2];
    const float* tab  = (const float*)d_in[3];

    char* ws = (char*)d_ws;
    size_t off = 0;
    f16*   xb     = (f16*)(ws + off);   off += (size_t)MTOT * 256 * 2;
    f16*   wqkvT  = (f16*)(ws + off);   off += (size_t)768 * 256 * 2;
    f16*   woutT  = (f16*)(ws + off);   off += (size_t)256 * 256 * 2;
    float* biasP  = (float*)(ws + off); off += (size_t)8 * NWP * NWP * 4;
    f16*   qkvb   = (f16*)(ws + off);   off += (size_t)MTOT * 768 * 2;
    f16*   ctxb   = (f16*)(ws + off);   off += (size_t)MTOT * 256 * 2;
    if (ws_size < off) return;

    cvt_x <<<MTOT * 256 / 1024, 256, 0, stream>>>(x, xb);
    prep_k<<<1024 + 8 * NWP * NWP / 256, 256, 0, stream>>>(wqkv, wout, tab, wqkvT, woutT, biasP);
    gemm_k<false><<<dim3(MTOT / 128, 768 / 128), 256, 0, stream>>>(xb, wqkvT, qkvb, 768);
    attn_k<<<128 * HEADS, 512, 0, stream>>>(qkvb, biasP, ctxb);
    gemm_k<true><<<dim3(MTOT / 128, 256 / 128), 256, 0, stream>>>(ctxb, woutT, d_out, 256);
}

// Round 7
// 245.853 us; speedup vs baseline: 1.3207x; 1.0189x over previous
//
#include <hip/hip_runtime.h>
#include <math.h>

using f16   = _Float16;
using f16x4 = __attribute__((ext_vector_type(4))) _Float16;
using f16x8 = __attribute__((ext_vector_type(8))) _Float16;
using f32x4 = __attribute__((ext_vector_type(4))) float;

#define NW    343           // tokens per window (7*7*7)
#define NWP   352           // padded to 22*16
#define VTP   356           // V^T LDS pitch (even -> b32 pair-writes stay aligned)
#define HEADS 8
#define MTOT  43904         // 128 windows * 343
#define LOG2E 1.4426950408889634f
#define QSC   (0.17677669529663687f * 1.4426950408889634f)  // dh^-0.5 * log2(e)

typedef const __attribute__((address_space(1))) unsigned int* gp1_t;
typedef __attribute__((address_space(3))) unsigned int* lp3_t;
__device__ __forceinline__ void gload_lds16(const void* g, void* l) {
    __builtin_amdgcn_global_load_lds((gp1_t)g, (lp3_t)l, 16, 0, 0);
}

// ---------------- converts ----------------
__global__ void cvt_x(const float* __restrict__ x, f16* __restrict__ xb) {
    int id = blockIdx.x * 256 + threadIdx.x;
    float4 v = *(const float4*)(x + id * 4);
    f16x4 o = { (f16)v.x, (f16)v.y, (f16)v.z, (f16)v.w };
    *(f16x4*)(xb + id * 4) = o;
}

// merged: wqkv^T (scaled q cols) | wout^T | padded bias table
__global__ void prep_k(const float* __restrict__ wqkv, const float* __restrict__ wout,
                       const float* __restrict__ tab,
                       f16* __restrict__ wqkvT, f16* __restrict__ woutT,
                       float* __restrict__ bp) {
    int b = blockIdx.x, t = threadIdx.x;
    if (b < 768) {                     // wqkv: n = b, k = t
        float v = wqkv[t * 768 + b];
        if (b < 256) v *= QSC;
        wqkvT[b * 256 + t] = (f16)v;
    } else if (b < 1024) {             // wout: n = b-768
        int n = b - 768;
        woutT[n * 256 + t] = (f16)wout[t * 256 + n];
    } else {                           // bias: bp[h][i][j]
        int id = (b - 1024) * 256 + t; // 8*352*352 exact
        int h = id / (NWP * NWP);
        int rem = id - h * NWP * NWP;
        int i = rem / NWP, j = rem - (rem / NWP) * NWP;
        float v;
        if (j >= NW) v = -1e30f;       // masked key col -> exp2 = 0
        else if (i >= NW) v = 0.f;
        else {
            int a1 = i / 49, a2 = (i / 7) % 7, a3 = i % 7;
            int b1 = j / 49, b2 = (j / 7) % 7, b3 = j % 7;
            int idx = (a1 - b1 + 6) * 169 + (a2 - b2 + 6) * 13 + (a3 - b3 + 6);
            v = tab[idx * 8 + h] * LOG2E;
        }
        bp[id] = v;
    }
}

// ---- GEMM: C(M x N) = A(M x 256) * Bt(N x 256)^T, 128x128 tile, BK=32, lds-DMA ----
// K=256 -> only 8 K-steps, so the epilogue matters: instead of 64 scalar stores
// per thread (2B/4B, quarter-coalesced), round-trip acc through LDS in 32-row
// chunks and emit fully-coalesced dwordx4 stores (8 insts f16 / 16 insts f32).
template<bool OUT_F32>
__launch_bounds__(256)
__global__ void gemm_k(const f16* __restrict__ A, const f16* __restrict__ Bt,
                       void* __restrict__ Cp, int N) {
    __shared__ __align__(16) unsigned char smem[16384];
    f16* As = (f16*)smem;              // [128][32]
    f16* Bs = (f16*)(smem + 8192);     // [128][32]
    const int m0 = blockIdx.x * 128;
    const int n0 = blockIdx.y * 128;
    const int t = threadIdx.x;
    const int wave = t >> 6, lane = t & 63;
    const int q = lane >> 4, c = lane & 15;
    const int wm = (wave >> 1) * 64, wn = (wave & 1) * 64;
    const int r0 = t >> 2;
    const int c8 = (t & 3) * 8;

    f32x4 acc[4][4] = {};
#pragma unroll
    for (int ks = 0; ks < 256; ks += 32) {
        gload_lds16(&A[(size_t)(m0 + r0) * 256 + ks + c8],        &As[r0 * 32 + c8]);
        gload_lds16(&A[(size_t)(m0 + r0 + 64) * 256 + ks + c8],   &As[(r0 + 64) * 32 + c8]);
        gload_lds16(&Bt[(size_t)(n0 + r0) * 256 + ks + c8],       &Bs[r0 * 32 + c8]);
        gload_lds16(&Bt[(size_t)(n0 + r0 + 64) * 256 + ks + c8],  &Bs[(r0 + 64) * 32 + c8]);
        __syncthreads();
        f16x8 af[4], bf[4];
#pragma unroll
        for (int a = 0; a < 4; a++) af[a] = *(const f16x8*)&As[(wm + a * 16 + c) * 32 + q * 8];
#pragma unroll
        for (int b = 0; b < 4; b++) bf[b] = *(const f16x8*)&Bs[(wn + b * 16 + c) * 32 + q * 8];
#pragma unroll
        for (int a = 0; a < 4; a++)
#pragma unroll
            for (int b = 0; b < 4; b++)
                acc[a][b] = __builtin_amdgcn_mfma_f32_16x16x32_f16(af[a], bf[b], acc[a][b], 0, 0, 0);
        __syncthreads();
    }
    // ---- epilogue: 4 chunks of 32 rows, LDS transpose -> coalesced stores ----
#pragma unroll
    for (int g = 0; g < 4; g++) {
        if (wm == (g >> 1) * 64) {
            const int a0 = (g & 1) * 2;
#pragma unroll
            for (int a = a0; a < a0 + 2; a++)
#pragma unroll
                for (int b = 0; b < 4; b++)
#pragma unroll
                    for (int r = 0; r < 4; r++) {
                        int row_loc = (a - a0) * 16 + q * 4 + r;
                        int col = wn + b * 16 + c;
                        if (OUT_F32) ((float*)smem)[row_loc * 128 + col] = acc[a][b][r];
                        else         ((f16*)smem)[row_loc * 128 + col] = (f16)acc[a][b][r];
                    }
        }
        __syncthreads();
        const int flat = t * 16;                 // 16 elems/thread, 4096 elems/chunk
        const int row_loc = flat >> 7, col = flat & 127;
        if (OUT_F32) {
            float* dst = (float*)Cp + (size_t)(m0 + g * 32 + row_loc) * N + n0 + col;
            const float* src = (const float*)smem + flat;
#pragma unroll
            for (int it = 0; it < 4; it++)
                *(float4*)(dst + it * 4) = *(const float4*)(src + it * 4);
        } else {
            f16* dst = (f16*)Cp + (size_t)(m0 + g * 32 + row_loc) * N + n0 + col;
            const f16* src = (const f16*)smem + flat;
#pragma unroll
            for (int it = 0; it < 2; it++)
                *(uint4*)(dst + it * 8) = *(const uint4*)(src + it * 8);
        }
        __syncthreads();
    }
}

// -------- fused attention: 1 block = (window, head), 8 waves share K/V LDS --------
// Max-free softmax (logits O(10); masked keys bias=-1e30 -> p=0). Bias is added
// AFTER the MFMA (C-operand bias in R6 put the ~200cyc L2 load on the MFMA
// issue chain: 86->107us). Depth-1 prefetch of next kf/b4 overlaps their
// latency with the current MFMA+exp2 chain.
__launch_bounds__(512)
__global__ void attn_k(const f16* __restrict__ qkv, const float* __restrict__ biasP,
                       f16* __restrict__ ctx) {
    const int w = blockIdx.x >> 3;
    const int h = blockIdx.x & 7;
    __shared__ f16 Ks[NWP * 32];       // [key][feat]
    __shared__ f16 Vt[32 * VTP];       // [dh][key] (transposed)
    const int t = threadIdx.x;
    const size_t base = (size_t)(w * NW) * 768;

    for (int u = t; u < NWP * 4; u += 512) {
        int row = u >> 2, un = u & 3;
        uint4 val;
        if (row < NW) val = *(const uint4*)&qkv[base + (size_t)row * 768 + 256 + h * 32 + un * 8];
        else { val.x = val.y = val.z = val.w = 0u; }
        *(uint4*)&Ks[row * 32 + un * 8] = val;
    }
    // V^T staging: token-pair packed b32 writes
    for (int u = t; u < (NWP / 2) * 4; u += 512) {
        int pr = u >> 2, un = u & 3;
        int row = pr * 2;
        uint4 v0, v1;
        v0.x = v0.y = v0.z = v0.w = 0u;
        v1 = v0;
        if (row < NW)     v0 = *(const uint4*)&qkv[base + (size_t)row * 768 + 512 + h * 32 + un * 8];
        if (row + 1 < NW) v1 = *(const uint4*)&qkv[base + (size_t)(row + 1) * 768 + 512 + h * 32 + un * 8];
        const unsigned short* a = (const unsigned short*)&v0;
        const unsigned short* b = (const unsigned short*)&v1;
#pragma unroll
        for (int e = 0; e < 8; e++) {
            unsigned int packed = (unsigned int)a[e] | ((unsigned int)b[e] << 16);
            *(unsigned int*)&Vt[(un * 8 + e) * VTP + row] = packed;
        }
    }
    __syncthreads();

    const int wave = t >> 6, lane = t & 63;
    const int q = lane >> 4, c = lane & 15;
    const float* biasH = biasP + (size_t)h * NWP * NWP;

    for (int qt = wave; qt < NWP / 16; qt += 8) {
        const int iq = qt * 16 + c;                 // this lane's query (col axis)
        const int iqc = iq < NW ? iq : NW - 1;
        f16x8 qf = *(const f16x8*)&qkv[base + (size_t)iqc * 768 + h * 32 + q * 8];
        const float* brow = biasH + (size_t)iq * NWP;

        f32x4 o0 = {0.f, 0.f, 0.f, 0.f}, o1 = {0.f, 0.f, 0.f, 0.f};
        float lsum = 0.f;
        f16x8 kf = *(const f16x8*)&Ks[c * 32 + q * 8];
        f32x4 b4 = *(const f32x4*)&brow[q * 4];
#pragma unroll
        for (int jt = 0; jt < NWP / 16; jt++) {
            const int jb = jt * 16;
            f16x8 kfn; f32x4 b4n;
            if (jt < NWP / 16 - 1) {               // depth-1 prefetch
                kfn = *(const f16x8*)&Ks[(jb + 16 + c) * 32 + q * 8];
                b4n = *(const f32x4*)&brow[jb + 16 + q * 4];
            }
            // S^T tile: rows = keys (reg axis), cols = queries (lane axis)
            f32x4 z = {0.f, 0.f, 0.f, 0.f};
            f32x4 s = __builtin_amdgcn_mfma_f32_16x16x32_f16(kf, qf, z, 0, 0, 0);
            float p0 = __builtin_amdgcn_exp2f(s[0] + b4[0]);
            float p1 = __builtin_amdgcn_exp2f(s[1] + b4[1]);
            float p2 = __builtin_amdgcn_exp2f(s[2] + b4[2]);
            float p3 = __builtin_amdgcn_exp2f(s[3] + b4[3]);
            lsum += (p0 + p1) + (p2 + p3);
            // P regs are already the B-operand of P^T for 16x16x16: O^T += V^T P^T
            f16x4 pf = { (f16)p0, (f16)p1, (f16)p2, (f16)p3 };
            f16x4 v0 = *(const f16x4*)&Vt[c * VTP + jb + q * 4];
            f16x4 v1 = *(const f16x4*)&Vt[(16 + c) * VTP + jb + q * 4];
            o0 = __builtin_amdgcn_mfma_f32_16x16x16f16(v0, pf, o0, 0, 0, 0);
            o1 = __builtin_amdgcn_mfma_f32_16x16x16f16(v1, pf, o1, 0, 0, 0);
            kf = kfn; b4 = b4n;
        }
        lsum += __shfl_xor(lsum, 16);   // reduce over quads, once per q-tile
        lsum += __shfl_xor(lsum, 32);

        if (iq < NW) {
            float inv = 1.f / lsum;
            size_t ob = (size_t)(w * NW + iq) * 256 + h * 32;
            f16x4 s0 = { (f16)(o0[0] * inv), (f16)(o0[1] * inv),
                         (f16)(o0[2] * inv), (f16)(o0[3] * inv) };
            f16x4 s1 = { (f16)(o1[0] * inv), (f16)(o1[1] * inv),
                         (f16)(o1[2] * inv), (f16)(o1[3] * inv) };
            *(f16x4*)&ctx[ob + q * 4] = s0;
            *(f16x4*)&ctx[ob + 16 + q * 4] = s1;
        }
    }
}

// ---------------- launch ----------------
extern "C" void kernel_launch(void* const* d_in, const int* in_sizes, int n_in,
                              void* d_out, int out_size, void* d_ws, size_t ws_size,
                              hipStream_t stream) {
    const float* x    = (const float*)d_in[0];
    const float* wqkv = (const float*)d_in[1];
    const float* wout = (const float*)d_in[2];
    const float* tab  = (const float*)d_in[3];

    char* ws = (char*)d_ws;
    size_t off = 0;
    f16*   xb     = (f16*)(ws + off);   off += (size_t)MTOT * 256 * 2;
    f16*   wqkvT  = (f16*)(ws + off);   off += (size_t)768 * 256 * 2;
    f16*   woutT  = (f16*)(ws + off);   off += (size_t)256 * 256 * 2;
    float* biasP  = (float*)(ws + off); off += (size_t)8 * NWP * NWP * 4;
    f16*   qkvb   = (f16*)(ws + off);   off += (size_t)MTOT * 768 * 2;
    f16*   ctxb   = (f16*)(ws + off);   off += (size_t)MTOT * 256 * 2;
    if (ws_size < off) return;

    cvt_x <<<MTOT * 256 / 1024, 256, 0, stream>>>(x, xb);
    prep_k<<<1024 + 8 * NWP * NWP / 256, 256, 0, stream>>>(wqkv, wout, tab, wqkvT, woutT, biasP);
    gemm_k<false><<<dim3(MTOT / 128, 768 / 128), 256, 0, stream>>>(xb, wqkvT, qkvb, 768);
    attn_k<<<128 * HEADS, 512, 0, stream>>>(qkvb, biasP, ctxb);
    gemm_k<true><<<dim3(MTOT / 128, 256 / 128), 256, 0, stream>>>(ctxb, woutT, d_out, 256);
}